// Round 1
// baseline (504.416 us; speedup 1.0000x reference)
//
#include <hip/hip_runtime.h>
#include <hip/hip_bf16.h>
#include <stdint.h>
#include <math.h>

#define HIDDEN 768
#define BATCH 4
#define SEQ 8192
#define NQ 1024

typedef __bf16 bf16;
typedef __bf16 bf16x4 __attribute__((ext_vector_type(4)));
typedef __bf16 bf16x8 __attribute__((ext_vector_type(8)));
typedef float f32x4 __attribute__((ext_vector_type(4)));

// ---------------------------------------------------------------------------
// fp32 -> bf16 elementwise convert (float4 vectorized, grid-stride)
__global__ __launch_bounds__(256) void k_cvt(const float* __restrict__ in,
                                             bf16* __restrict__ out, int n4) {
  int stride = gridDim.x * blockDim.x;
  for (int i = blockIdx.x * blockDim.x + threadIdx.x; i < n4; i += stride) {
    float4 v = reinterpret_cast<const float4*>(in)[i];
    bf16x4 o = {(bf16)v.x, (bf16)v.y, (bf16)v.z, (bf16)v.w};
    reinterpret_cast<bf16x4*>(out)[i] = o;
  }
}

// ---------------------------------------------------------------------------
// [R][C] (TIN) -> [C][R] (bf16) tiled transpose-convert. R,C multiples of 32.
template <typename TIN>
__global__ __launch_bounds__(256) void k_transpose_bf16(
    const TIN* __restrict__ in, bf16* __restrict__ out, int R, int C,
    long inBatchStride, long outBatchStride) {
  __shared__ float tile[32][33];
  const long bIn = (long)blockIdx.z * inBatchStride;
  const long bOut = (long)blockIdx.z * outBatchStride;
  const int c0 = blockIdx.x * 32, r0 = blockIdx.y * 32;
  const int tx = threadIdx.x & 31, ty = threadIdx.x >> 5;  // 32 x 8
#pragma unroll
  for (int i = 0; i < 32; i += 8)
    tile[ty + i][tx] = (float)in[bIn + (long)(r0 + ty + i) * C + (c0 + tx)];
  __syncthreads();
#pragma unroll
  for (int i = 0; i < 32; i += 8)
    out[bOut + (long)(c0 + ty + i) * R + (r0 + tx)] = (bf16)tile[tx][ty + i];
}

// ---------------------------------------------------------------------------
// C[M,N] = (A[M,K] . B[N,K]^T) * scale + bias[col]
// m97 structure: 128x128 tile, BK=32, 4 waves (2x2 of 64x64), 16x16x32 MFMA,
// global_load_lds width 16, single-buffered LDS, 2 barriers per K-step.
// blockIdx.z batches A/B/C by the given element strides.
template <typename OUT>
__global__ __launch_bounds__(256) void k_gemm_bt(
    const bf16* __restrict__ A, const bf16* __restrict__ B, OUT* __restrict__ C,
    const float* __restrict__ bias, int M, int N, int K, float scale,
    long strA, long strB, long strC) {
  A += (long)blockIdx.z * strA;
  B += (long)blockIdx.z * strB;
  C += (long)blockIdx.z * strC;

  __shared__ bf16 sA[128 * 32];
  __shared__ bf16 sB[128 * 32];

  const int tid = threadIdx.x;
  const int lane = tid & 63;
  const int wave = tid >> 6;
  const int wr = wave >> 1, wc = wave & 1;
  const int lr = lane & 15;          // fragment row (A) / col (B)
  const int lk = (lane >> 4) * 8;    // k offset within fragment

  const bf16* At = A + (long)blockIdx.y * 128 * K;
  const bf16* Bt = B + (long)blockIdx.x * 128 * K;

  f32x4 acc[4][4] = {};

  for (int k0 = 0; k0 < K; k0 += 32) {
    // stage 128x32 bf16 tiles of A and B: 512 chunks of 16B each, 2/thread
#pragma unroll
    for (int h = 0; h < 2; ++h) {
      const int c = tid + h * 256;
      const int row = c >> 2;
      const int col = (c & 3) * 8;
      const bf16* ga = At + (long)row * K + k0 + col;
      const bf16* gb = Bt + (long)row * K + k0 + col;
      __builtin_amdgcn_global_load_lds(
          (const __attribute__((address_space(1))) void*)ga,
          (__attribute__((address_space(3))) void*)((char*)sA + c * 16), 16, 0, 0);
      __builtin_amdgcn_global_load_lds(
          (const __attribute__((address_space(1))) void*)gb,
          (__attribute__((address_space(3))) void*)((char*)sB + c * 16), 16, 0, 0);
    }
    __syncthreads();

    bf16x8 af[4], bfr[4];
#pragma unroll
    for (int m = 0; m < 4; ++m)
      af[m] = *reinterpret_cast<const bf16x8*>(&sA[(wr * 64 + m * 16 + lr) * 32 + lk]);
#pragma unroll
    for (int n = 0; n < 4; ++n)
      bfr[n] = *reinterpret_cast<const bf16x8*>(&sB[(wc * 64 + n * 16 + lr) * 32 + lk]);
#pragma unroll
    for (int m = 0; m < 4; ++m)
#pragma unroll
      for (int n = 0; n < 4; ++n)
        acc[m][n] = __builtin_amdgcn_mfma_f32_16x16x32_bf16(af[m], bfr[n], acc[m][n], 0, 0, 0);
    __syncthreads();
  }

  // epilogue: C/D layout col = lane&15, row = (lane>>4)*4 + j  [m89-verified]
  const int lg = (lane >> 4) * 4;
#pragma unroll
  for (int m = 0; m < 4; ++m) {
#pragma unroll
    for (int n = 0; n < 4; ++n) {
      const int col = blockIdx.x * 128 + wc * 64 + n * 16 + lr;
      const float bv = bias ? bias[col] : 0.0f;
#pragma unroll
      for (int j = 0; j < 4; ++j) {
        const int row = blockIdx.y * 128 + wr * 64 + m * 16 + lg + j;
        C[(long)row * N + col] = (OUT)(acc[m][n][j] * scale + bv);
      }
    }
  }
}

// ---------------------------------------------------------------------------
// Row softmax over SEQ with additive mask bias, in-place on bf16 probs.
// One 256-thread block per row; 32 values/thread kept in registers.
__global__ __launch_bounds__(256) void k_softmax(bf16* __restrict__ P,
                                                 const float* __restrict__ mask) {
  const int row = blockIdx.x;             // b * NQ + q
  bf16* p = P + (long)row * SEQ;
  const float* mrow = mask + (long)(row >> 10) * SEQ;  // NQ = 1024
  const int t = threadIdx.x;

  float v[32];
  float mx = -3.0e38f;
#pragma unroll
  for (int c = 0; c < 4; ++c) {
    const int base = (c * 256 + t) * 8;
    bf16x8 raw = *reinterpret_cast<const bf16x8*>(p + base);
#pragma unroll
    for (int j = 0; j < 8; ++j) {
      const float mb = (1.0f - mrow[base + j]) * -10000.0f;
      const float s = (float)raw[j] + mb;
      v[c * 8 + j] = s;
      mx = fmaxf(mx, s);
    }
  }
#pragma unroll
  for (int o = 32; o > 0; o >>= 1) mx = fmaxf(mx, __shfl_xor(mx, o));
  __shared__ float redm[4];
  __shared__ float reds[4];
  const int wave = t >> 6, lane = t & 63;
  if (lane == 0) redm[wave] = mx;
  __syncthreads();
  mx = fmaxf(fmaxf(redm[0], redm[1]), fmaxf(redm[2], redm[3]));

  float sum = 0.0f;
#pragma unroll
  for (int i = 0; i < 32; ++i) {
    v[i] = expf(v[i] - mx);
    sum += v[i];
  }
#pragma unroll
  for (int o = 32; o > 0; o >>= 1) sum += __shfl_xor(sum, o);
  if (lane == 0) reds[wave] = sum;
  __syncthreads();
  sum = reds[0] + reds[1] + reds[2] + reds[3];
  const float inv = 1.0f / sum;

#pragma unroll
  for (int c = 0; c < 4; ++c) {
    const int base = (c * 256 + t) * 8;
    bf16x8 o;
#pragma unroll
    for (int j = 0; j < 8; ++j) o[j] = (bf16)(v[c * 8 + j] * inv);
    *reinterpret_cast<bf16x8*>(p + base) = o;
  }
}

// ---------------------------------------------------------------------------
extern "C" void kernel_launch(void* const* d_in, const int* in_sizes, int n_in,
                              void* d_out, int out_size, void* d_ws, size_t ws_size,
                              hipStream_t stream) {
  const float* hs = (const float*)d_in[0];    // [B,S,H]
  const float* qu = (const float*)d_in[1];    // [B,Q,H]
  const float* mask = (const float*)d_in[2];  // [B,S]
  const float* Wq = (const float*)d_in[3];
  const float* bq = (const float*)d_in[4];
  const float* Wk = (const float*)d_in[5];
  const float* bk = (const float*)d_in[6];
  const float* Wv = (const float*)d_in[7];
  const float* bv = (const float*)d_in[8];
  float* out = (float*)d_out;                 // [B,Q,H] fp32

  const size_t HS_N = (size_t)BATCH * SEQ * HIDDEN;  // 25,165,824
  const size_t QU_N = (size_t)BATCH * NQ * HIDDEN;   //  3,145,728
  const size_t W_N = (size_t)HIDDEN * HIDDEN;
  const size_t P_N = (size_t)BATCH * NQ * SEQ;       // 33,554,432

  char* ws = (char*)d_ws;
  size_t off = 0;
  auto alloc = [&](size_t bytes) {
    char* p = ws + off;
    off += (bytes + 255) & ~(size_t)255;
    return p;
  };

  // region 0 (67.1 MB): probs (late) overlaps hidden_bf16/queries_bf16/W^T (early)
  char* region0 = alloc(P_N * 2);
  bf16* Pr = (bf16*)region0;
  bf16* hsb = (bf16*)region0;                           // 50.3 MB
  bf16* qub = (bf16*)(region0 + HS_N * 2);              //  6.3 MB
  bf16* WqT = (bf16*)(region0 + HS_N * 2 + QU_N * 2);   //  1.2 MB each
  bf16* WkT = WqT + W_N;
  bf16* WvT = WkT + W_N;

  bf16* Kb = (bf16*)alloc(HS_N * 2);  // [B*S][H] bf16
  bf16* Vb = (bf16*)alloc(HS_N * 2);  // [B*S][H] bf16
  bf16* VT = (bf16*)alloc(HS_N * 2);  // per-batch [H][S] bf16
  bf16* Qb = (bf16*)alloc(QU_N * 2);  // [B*Q][H] bf16

  // 1) converts
  k_cvt<<<dim3(2048), dim3(256), 0, stream>>>(hs, hsb, (int)(HS_N / 4));
  k_cvt<<<dim3(1024), dim3(256), 0, stream>>>(qu, qub, (int)(QU_N / 4));

  // 2) W transposes (fp32 -> bf16, [H][D] -> [D][H])
  k_transpose_bf16<float><<<dim3(24, 24, 1), dim3(256), 0, stream>>>(Wq, WqT, HIDDEN, HIDDEN, 0, 0);
  k_transpose_bf16<float><<<dim3(24, 24, 1), dim3(256), 0, stream>>>(Wk, WkT, HIDDEN, HIDDEN, 0, 0);
  k_transpose_bf16<float><<<dim3(24, 24, 1), dim3(256), 0, stream>>>(Wv, WvT, HIDDEN, HIDDEN, 0, 0);

  // 3) projections: K = hs.WkT^T + bk ; V = hs.WvT^T + bv ; Q = qu.WqT^T + bq
  k_gemm_bt<bf16><<<dim3(6, 256, 1), dim3(256), 0, stream>>>(
      hsb, WkT, Kb, bk, BATCH * SEQ, HIDDEN, HIDDEN, 1.0f, 0, 0, 0);
  k_gemm_bt<bf16><<<dim3(6, 256, 1), dim3(256), 0, stream>>>(
      hsb, WvT, Vb, bv, BATCH * SEQ, HIDDEN, HIDDEN, 1.0f, 0, 0, 0);
  k_gemm_bt<bf16><<<dim3(6, 32, 1), dim3(256), 0, stream>>>(
      qub, WqT, Qb, bq, BATCH * NQ, HIDDEN, HIDDEN, 1.0f, 0, 0, 0);

  // 4) V transpose per batch: [S][H] -> [H][S]
  k_transpose_bf16<bf16><<<dim3(24, 256, 4), dim3(256), 0, stream>>>(
      Vb, VT, SEQ, HIDDEN, (long)SEQ * HIDDEN, (long)HIDDEN * SEQ);

  // 5) scores: Pr[b] = Q[b].K[b]^T / sqrt(H)   (bf16, 1024x8192 per batch)
  const float qkscale = 1.0f / sqrtf((float)HIDDEN);
  k_gemm_bt<bf16><<<dim3(64, 8, 4), dim3(256), 0, stream>>>(
      Qb, Kb, Pr, nullptr, NQ, SEQ, HIDDEN, qkscale,
      (long)NQ * HIDDEN, (long)SEQ * HIDDEN, (long)NQ * SEQ);

  // 6) softmax rows (in-place, with mask bias)
  k_softmax<<<dim3(BATCH * NQ), dim3(256), 0, stream>>>(Pr, mask);

  // 7) context: out[b] = Pr[b].VT[b]^T  (fp32 out)
  k_gemm_bt<float><<<dim3(6, 8, 4), dim3(256), 0, stream>>>(
      Pr, VT, out, nullptr, NQ, HIDDEN, SEQ, 1.0f,
      (long)NQ * SEQ, (long)HIDDEN * SEQ, (long)NQ * HIDDEN);
}

// Round 2
// 494.648 us; speedup vs baseline: 1.0197x; 1.0197x over previous
//
#include <hip/hip_runtime.h>
#include <hip/hip_bf16.h>
#include <stdint.h>
#include <math.h>

#define HIDDEN 768
#define BATCH 4
#define SEQ 8192
#define NQ 1024

typedef __bf16 bf16;
typedef __bf16 bf16x4 __attribute__((ext_vector_type(4)));
typedef __bf16 bf16x8 __attribute__((ext_vector_type(8)));
typedef float f32x4 __attribute__((ext_vector_type(4)));

// Bijective XCD-chunked block-id swizzle (requires gridDim.x % 8 == 0).
// HW round-robins consecutive blockIdx across the 8 XCDs; this remap gives
// each XCD a contiguous chunk of the logical grid so neighbor tiles share L2.
__device__ inline int xcd_swz() {
  const int o = blockIdx.x;
  const int chunk = gridDim.x >> 3;
  return (o & 7) * chunk + (o >> 3);
}

// ---------------------------------------------------------------------------
// fp32 -> bf16 elementwise convert (float4 vectorized, grid-stride)
__global__ __launch_bounds__(256) void k_cvt(const float* __restrict__ in,
                                             bf16* __restrict__ out, int n4) {
  int stride = gridDim.x * blockDim.x;
  for (int i = blockIdx.x * blockDim.x + threadIdx.x; i < n4; i += stride) {
    float4 v = reinterpret_cast<const float4*>(in)[i];
    bf16x4 o = {(bf16)v.x, (bf16)v.y, (bf16)v.z, (bf16)v.w};
    reinterpret_cast<bf16x4*>(out)[i] = o;
  }
}

// ---------------------------------------------------------------------------
// [R][C] (TIN) -> [C][R] (bf16) tiled transpose-convert. R,C multiples of 32.
template <typename TIN>
__global__ __launch_bounds__(256) void k_transpose_bf16(
    const TIN* __restrict__ in, bf16* __restrict__ out, int R, int C,
    long inBatchStride, long outBatchStride) {
  __shared__ float tile[32][33];
  const long bIn = (long)blockIdx.z * inBatchStride;
  const long bOut = (long)blockIdx.z * outBatchStride;
  const int c0 = blockIdx.x * 32, r0 = blockIdx.y * 32;
  const int tx = threadIdx.x & 31, ty = threadIdx.x >> 5;  // 32 x 8
#pragma unroll
  for (int i = 0; i < 32; i += 8)
    tile[ty + i][tx] = (float)in[bIn + (long)(r0 + ty + i) * C + (c0 + tx)];
  __syncthreads();
#pragma unroll
  for (int i = 0; i < 32; i += 8)
    out[bOut + (long)(c0 + ty + i) * R + (r0 + tx)] = (bf16)tile[tx][ty + i];
}

#define GLOAD16(gptr, lptr)                                                   \
  __builtin_amdgcn_global_load_lds(                                           \
      (const __attribute__((address_space(1))) void*)(gptr),                  \
      (__attribute__((address_space(3))) void*)(lptr), 16, 0, 0)

// ---------------------------------------------------------------------------
// C[M,N] = (A[M,K] . B[N,K]^T) * scale + bias[col]; optional dual-B/dual-C
// (fused K & V projection: one A staging feeds two MFMA streams).
// m97 structure: 128x128 tile, BK=32, 4 waves (2x2 of 64x64), 16x16x32 MFMA,
// global_load_lds width 16. 1-D grid, XCD-chunked swizzle, col index fastest.
template <typename OUT, bool DUAL>
__global__ __launch_bounds__(256) void k_gemm_bt(
    const bf16* __restrict__ A, const bf16* __restrict__ B0,
    const bf16* __restrict__ B1, OUT* __restrict__ C0, OUT* __restrict__ C1,
    const float* __restrict__ bias0, const float* __restrict__ bias1,
    int N, int K, float scale, int nx, int ny,
    long strA, long strB, long strC) {
  const int id = xcd_swz();
  const int col = id % nx;
  const int rest = id / nx;
  const int row = rest % ny;
  const int z = rest / ny;

  __shared__ bf16 sA[128 * 32];
  __shared__ bf16 sB0[128 * 32];
  __shared__ bf16 sB1[DUAL ? 128 * 32 : 1];

  const int tid = threadIdx.x;
  const int lane = tid & 63;
  const int wave = tid >> 6;
  const int wr = wave >> 1, wc = wave & 1;
  const int lr = lane & 15;
  const int lk = (lane >> 4) * 8;

  const bf16* At = A + (long)z * strA + (long)row * 128 * K;
  const bf16* Bt0 = B0 + (long)z * strB + (long)col * 128 * K;
  const bf16* Bt1 = DUAL ? B1 + (long)z * strB + (long)col * 128 * K : nullptr;

  f32x4 acc0[4][4] = {};
  f32x4 acc1[DUAL ? 4 : 1][DUAL ? 4 : 1] = {};

  for (int k0 = 0; k0 < K; k0 += 32) {
#pragma unroll
    for (int h = 0; h < 2; ++h) {
      const int c = tid + h * 256;
      const int r = c >> 2;
      const int cc = (c & 3) * 8;
      GLOAD16(At + (long)r * K + k0 + cc, (char*)sA + c * 16);
      GLOAD16(Bt0 + (long)r * K + k0 + cc, (char*)sB0 + c * 16);
      if (DUAL) GLOAD16(Bt1 + (long)r * K + k0 + cc, (char*)sB1 + c * 16);
    }
    __syncthreads();

    bf16x8 af[4], bf0[4], bf1[4];
#pragma unroll
    for (int m = 0; m < 4; ++m)
      af[m] = *reinterpret_cast<const bf16x8*>(&sA[(wr * 64 + m * 16 + lr) * 32 + lk]);
#pragma unroll
    for (int n = 0; n < 4; ++n) {
      bf0[n] = *reinterpret_cast<const bf16x8*>(&sB0[(wc * 64 + n * 16 + lr) * 32 + lk]);
      if (DUAL)
        bf1[n] = *reinterpret_cast<const bf16x8*>(&sB1[(wc * 64 + n * 16 + lr) * 32 + lk]);
    }
#pragma unroll
    for (int m = 0; m < 4; ++m)
#pragma unroll
      for (int n = 0; n < 4; ++n) {
        acc0[m][n] = __builtin_amdgcn_mfma_f32_16x16x32_bf16(af[m], bf0[n], acc0[m][n], 0, 0, 0);
        if (DUAL)
          acc1[m][n] = __builtin_amdgcn_mfma_f32_16x16x32_bf16(af[m], bf1[n], acc1[m][n], 0, 0, 0);
      }
    __syncthreads();
  }

  // epilogue: C/D layout col = lane&15, row = (lane>>4)*4 + j  [m89-verified]
  const int lg = (lane >> 4) * 4;
  OUT* Cb0 = C0 + (long)z * strC;
  OUT* Cb1 = DUAL ? C1 + (long)z * strC : nullptr;
#pragma unroll
  for (int m = 0; m < 4; ++m) {
#pragma unroll
    for (int n = 0; n < 4; ++n) {
      const int gc = col * 128 + wc * 64 + n * 16 + lr;
      const float bv0 = bias0 ? bias0[gc] : 0.0f;
      const float bv1 = (DUAL && bias1) ? bias1[gc] : 0.0f;
#pragma unroll
      for (int j = 0; j < 4; ++j) {
        const int gr = row * 128 + wr * 64 + m * 16 + lg + j;
        Cb0[(long)gr * N + gc] = (OUT)(acc0[m][n][j] * scale + bv0);
        if (DUAL) Cb1[(long)gr * N + gc] = (OUT)(acc1[m][n][j] * scale + bv1);
      }
    }
  }
}

// ---------------------------------------------------------------------------
// PV split-K partial GEMM: Cpart[kc,b,q,:] = P[b, q-tile, kc-chunk] . VT^T
// P: [B][NQ][SEQ] bf16, VT: [B][HIDDEN][SEQ] bf16, Cpart fp32.
// KS=4 chunks of 2048 -> grid 6*8*4*4 = 768 blocks (parallelism fix).
#define PV_KS 4
#define PV_KC (SEQ / PV_KS)
__global__ __launch_bounds__(256) void k_gemm_pv(const bf16* __restrict__ P,
                                                 const bf16* __restrict__ VT,
                                                 float* __restrict__ Cp) {
  const int id = xcd_swz();
  const int col = id % 6;
  int r = id / 6;
  const int row = r % 8;
  r /= 8;
  const int b = r % 4;
  const int kc = r / 4;

  __shared__ bf16 sA[128 * 32];
  __shared__ bf16 sB[128 * 32];

  const int tid = threadIdx.x;
  const int lane = tid & 63;
  const int wave = tid >> 6;
  const int wr = wave >> 1, wc = wave & 1;
  const int lr = lane & 15;
  const int lk = (lane >> 4) * 8;

  const bf16* At = P + (long)b * NQ * SEQ + (long)row * 128 * SEQ + (long)kc * PV_KC;
  const bf16* Bt = VT + (long)b * HIDDEN * SEQ + (long)col * 128 * SEQ + (long)kc * PV_KC;

  f32x4 acc[4][4] = {};

  for (int k0 = 0; k0 < PV_KC; k0 += 32) {
#pragma unroll
    for (int h = 0; h < 2; ++h) {
      const int c = tid + h * 256;
      const int rr = c >> 2;
      const int cc = (c & 3) * 8;
      GLOAD16(At + (long)rr * SEQ + k0 + cc, (char*)sA + c * 16);
      GLOAD16(Bt + (long)rr * SEQ + k0 + cc, (char*)sB + c * 16);
    }
    __syncthreads();

    bf16x8 af[4], bfr[4];
#pragma unroll
    for (int m = 0; m < 4; ++m)
      af[m] = *reinterpret_cast<const bf16x8*>(&sA[(wr * 64 + m * 16 + lr) * 32 + lk]);
#pragma unroll
    for (int n = 0; n < 4; ++n)
      bfr[n] = *reinterpret_cast<const bf16x8*>(&sB[(wc * 64 + n * 16 + lr) * 32 + lk]);
#pragma unroll
    for (int m = 0; m < 4; ++m)
#pragma unroll
      for (int n = 0; n < 4; ++n)
        acc[m][n] = __builtin_amdgcn_mfma_f32_16x16x32_bf16(af[m], bfr[n], acc[m][n], 0, 0, 0);
    __syncthreads();
  }

  float* Co = Cp + ((long)kc * BATCH + b) * NQ * HIDDEN;
  const int lg = (lane >> 4) * 4;
#pragma unroll
  for (int m = 0; m < 4; ++m) {
#pragma unroll
    for (int n = 0; n < 4; ++n) {
      const int gc = col * 128 + wc * 64 + n * 16 + lr;
#pragma unroll
      for (int j = 0; j < 4; ++j) {
        const int gr = row * 128 + wr * 64 + m * 16 + lg + j;
        Co[(long)gr * HIDDEN + gc] = acc[m][n][j];
      }
    }
  }
}

// out = p0 + p1 + p2 + p3 (fp32, float4 vectorized)
__global__ __launch_bounds__(256) void k_reduce4(const float* __restrict__ p,
                                                 float* __restrict__ out, int n4) {
  const long NB = (long)BATCH * NQ * HIDDEN;
  const int stride = gridDim.x * blockDim.x;
  for (int i = blockIdx.x * blockDim.x + threadIdx.x; i < n4; i += stride) {
    f32x4 a = reinterpret_cast<const f32x4*>(p)[i];
    f32x4 b = reinterpret_cast<const f32x4*>(p + NB)[i];
    f32x4 c = reinterpret_cast<const f32x4*>(p + 2 * NB)[i];
    f32x4 d = reinterpret_cast<const f32x4*>(p + 3 * NB)[i];
    reinterpret_cast<f32x4*>(out)[i] = (a + b) + (c + d);
  }
}

// ---------------------------------------------------------------------------
// Row softmax over SEQ with additive mask bias, in-place on bf16 probs.
__global__ __launch_bounds__(256) void k_softmax(bf16* __restrict__ P,
                                                 const float* __restrict__ mask) {
  const int row = blockIdx.x;  // b * NQ + q
  bf16* p = P + (long)row * SEQ;
  const float* mrow = mask + (long)(row >> 10) * SEQ;
  const int t = threadIdx.x;

  float v[32];
  float mx = -3.0e38f;
#pragma unroll
  for (int c = 0; c < 4; ++c) {
    const int base = (c * 256 + t) * 8;
    bf16x8 raw = *reinterpret_cast<const bf16x8*>(p + base);
#pragma unroll
    for (int j = 0; j < 8; ++j) {
      const float mb = (1.0f - mrow[base + j]) * -10000.0f;
      const float s = (float)raw[j] + mb;
      v[c * 8 + j] = s;
      mx = fmaxf(mx, s);
    }
  }
#pragma unroll
  for (int o = 32; o > 0; o >>= 1) mx = fmaxf(mx, __shfl_xor(mx, o));
  __shared__ float redm[4];
  __shared__ float reds[4];
  const int wave = t >> 6, lane = t & 63;
  if (lane == 0) redm[wave] = mx;
  __syncthreads();
  mx = fmaxf(fmaxf(redm[0], redm[1]), fmaxf(redm[2], redm[3]));

  float sum = 0.0f;
#pragma unroll
  for (int i = 0; i < 32; ++i) {
    v[i] = expf(v[i] - mx);
    sum += v[i];
  }
#pragma unroll
  for (int o = 32; o > 0; o >>= 1) sum += __shfl_xor(sum, o);
  if (lane == 0) reds[wave] = sum;
  __syncthreads();
  sum = reds[0] + reds[1] + reds[2] + reds[3];
  const float inv = 1.0f / sum;

#pragma unroll
  for (int c = 0; c < 4; ++c) {
    const int base = (c * 256 + t) * 8;
    bf16x8 o;
#pragma unroll
    for (int j = 0; j < 8; ++j) o[j] = (bf16)(v[c * 8 + j] * inv);
    *reinterpret_cast<bf16x8*>(p + base) = o;
  }
}

// ---------------------------------------------------------------------------
extern "C" void kernel_launch(void* const* d_in, const int* in_sizes, int n_in,
                              void* d_out, int out_size, void* d_ws, size_t ws_size,
                              hipStream_t stream) {
  const float* hs = (const float*)d_in[0];    // [B,S,H]
  const float* qu = (const float*)d_in[1];    // [B,Q,H]
  const float* mask = (const float*)d_in[2];  // [B,S]
  const float* Wq = (const float*)d_in[3];
  const float* bq = (const float*)d_in[4];
  const float* Wk = (const float*)d_in[5];
  const float* bk = (const float*)d_in[6];
  const float* Wv = (const float*)d_in[7];
  const float* bv = (const float*)d_in[8];
  float* out = (float*)d_out;  // [B,Q,H] fp32

  const size_t HS_N = (size_t)BATCH * SEQ * HIDDEN;
  const size_t QU_N = (size_t)BATCH * NQ * HIDDEN;
  const size_t W_N = (size_t)HIDDEN * HIDDEN;
  const size_t P_N = (size_t)BATCH * NQ * SEQ;

  char* ws = (char*)d_ws;
  size_t off = 0;
  auto alloc = [&](size_t bytes) {
    char* p = ws + off;
    off += (bytes + 255) & ~(size_t)255;
    return p;
  };

  // region 0 (67.1 MB): probs (late) overlap hidden_bf16/queries_bf16/W^T (early)
  char* region0 = alloc(P_N * 2);
  bf16* Pr = (bf16*)region0;
  bf16* hsb = (bf16*)region0;
  bf16* qub = (bf16*)(region0 + HS_N * 2);
  bf16* WqT = (bf16*)(region0 + HS_N * 2 + QU_N * 2);
  bf16* WkT = WqT + W_N;
  bf16* WvT = WkT + W_N;

  char* kbRegion = alloc(HS_N * 2);   // Kb early; PV partials (50 MB fp32) late
  bf16* Kb = (bf16*)kbRegion;
  float* Ppart = (float*)kbRegion;    // 4 * B*Q*H fp32 = 50,331,648 B exactly
  bf16* Vb = (bf16*)alloc(HS_N * 2);
  bf16* VT = (bf16*)alloc(HS_N * 2);
  bf16* Qb = (bf16*)alloc(QU_N * 2);

  // 1) converts
  k_cvt<<<dim3(2048), dim3(256), 0, stream>>>(hs, hsb, (int)(HS_N / 4));
  k_cvt<<<dim3(1024), dim3(256), 0, stream>>>(qu, qub, (int)(QU_N / 4));

  // 2) W transposes (fp32 -> bf16, [H][D] -> [D][H])
  k_transpose_bf16<float><<<dim3(24, 24, 1), dim3(256), 0, stream>>>(Wq, WqT, HIDDEN, HIDDEN, 0, 0);
  k_transpose_bf16<float><<<dim3(24, 24, 1), dim3(256), 0, stream>>>(Wk, WkT, HIDDEN, HIDDEN, 0, 0);
  k_transpose_bf16<float><<<dim3(24, 24, 1), dim3(256), 0, stream>>>(Wv, WvT, HIDDEN, HIDDEN, 0, 0);

  // 3) fused K+V projection (dual-output), then Q projection
  k_gemm_bt<bf16, true><<<dim3(1536), dim3(256), 0, stream>>>(
      hsb, WkT, WvT, Kb, Vb, bk, bv, HIDDEN, HIDDEN, 1.0f, 6, 256, 0, 0, 0);
  k_gemm_bt<bf16, false><<<dim3(192), dim3(256), 0, stream>>>(
      qub, WqT, nullptr, Qb, nullptr, bq, nullptr, HIDDEN, HIDDEN, 1.0f, 6, 32, 0, 0, 0);

  // 4) V transpose per batch: [S][H] -> [H][S]
  k_transpose_bf16<bf16><<<dim3(24, 256, 4), dim3(256), 0, stream>>>(
      Vb, VT, SEQ, HIDDEN, (long)SEQ * HIDDEN, (long)HIDDEN * SEQ);

  // 5) scores: Pr[b] = Q[b].K[b]^T / sqrt(H)
  const float qkscale = 1.0f / sqrtf((float)HIDDEN);
  k_gemm_bt<bf16, false><<<dim3(2048), dim3(256), 0, stream>>>(
      Qb, Kb, nullptr, Pr, nullptr, nullptr, nullptr, SEQ, HIDDEN, qkscale, 64, 8,
      (long)NQ * HIDDEN, (long)SEQ * HIDDEN, (long)NQ * SEQ);

  // 6) softmax rows (in-place, with mask bias)
  k_softmax<<<dim3(BATCH * NQ), dim3(256), 0, stream>>>(Pr, mask);

  // 7) context partials: Ppart[kc] = P[:, kc-chunk] . VT^T   (768 blocks)
  k_gemm_pv<<<dim3(6 * 8 * 4 * PV_KS), dim3(256), 0, stream>>>(Pr, VT, Ppart);

  // 8) reduce partials -> out
  k_reduce4<<<dim3(1024), dim3(256), 0, stream>>>(Ppart, out, (int)(QU_N / 4));
}

// Round 3
// 380.336 us; speedup vs baseline: 1.3262x; 1.3006x over previous
//
#include <hip/hip_runtime.h>
#include <hip/hip_bf16.h>
#include <stdint.h>
#include <math.h>

#define HIDDEN 768
#define BATCH 4
#define SEQ 8192
#define NQ 1024

typedef __bf16 bf16;
typedef __bf16 bf16x4 __attribute__((ext_vector_type(4)));
typedef __bf16 bf16x8 __attribute__((ext_vector_type(8)));
typedef float f32x4 __attribute__((ext_vector_type(4)));

// Bijective XCD-chunked block-id swizzle (requires gridDim.x % 8 == 0).
__device__ inline int xcd_swz() {
  const int o = blockIdx.x;
  const int chunk = gridDim.x >> 3;
  return (o & 7) * chunk + (o >> 3);
}

// ---------------------------------------------------------------------------
// fp32 -> bf16 elementwise convert (float4 vectorized, grid-stride)
__global__ __launch_bounds__(256) void k_cvt(const float* __restrict__ in,
                                             bf16* __restrict__ out, int n4) {
  int stride = gridDim.x * blockDim.x;
  for (int i = blockIdx.x * blockDim.x + threadIdx.x; i < n4; i += stride) {
    float4 v = reinterpret_cast<const float4*>(in)[i];
    bf16x4 o = {(bf16)v.x, (bf16)v.y, (bf16)v.z, (bf16)v.w};
    reinterpret_cast<bf16x4*>(out)[i] = o;
  }
}

// ---------------------------------------------------------------------------
// [R][C] fp32 -> [C][R] bf16 tiled transpose-convert (weights only).
__global__ __launch_bounds__(256) void k_transpose_w(
    const float* __restrict__ in, bf16* __restrict__ out, int R, int C) {
  __shared__ float tile[32][33];
  const int c0 = blockIdx.x * 32, r0 = blockIdx.y * 32;
  const int tx = threadIdx.x & 31, ty = threadIdx.x >> 5;  // 32 x 8
#pragma unroll
  for (int i = 0; i < 32; i += 8)
    tile[ty + i][tx] = in[(long)(r0 + ty + i) * C + (c0 + tx)];
  __syncthreads();
#pragma unroll
  for (int i = 0; i < 32; i += 8)
    out[(long)(c0 + ty + i) * R + (r0 + tx)] = (bf16)tile[tx][ty + i];
}

#define GLOAD16(gptr, lptr)                                                   \
  __builtin_amdgcn_global_load_lds(                                           \
      (const __attribute__((address_space(1))) void*)(gptr),                  \
      (__attribute__((address_space(3))) void*)(lptr), 16, 0, 0)

// ---------------------------------------------------------------------------
// C[M,N] = (A[M,K] . B[N,K]^T) * scale + bias[col]
// m97 structure: 128x128 tile, BK=32, 4 waves (2x2 of 64x64), 16x16x32 MFMA,
// global_load_lds width 16. 1-D grid with XCD-chunked swizzle.
// rowfast picks which logical dim is fastest-varying (L2 working-set tuning).
template <typename OUT>
__global__ __launch_bounds__(256) void k_gemm_bt(
    const bf16* __restrict__ A, const bf16* __restrict__ B, OUT* __restrict__ C,
    const float* __restrict__ bias, int N, int K, float scale,
    int nx, int ny, int rowfast, long strA, long strB, long strC) {
  const int id = xcd_swz();
  int col, row, z;
  if (rowfast) {
    row = id % ny; col = (id / ny) % nx; z = id / (ny * nx);
  } else {
    col = id % nx; row = (id / nx) % ny; z = id / (nx * ny);
  }

  __shared__ bf16 sA[128 * 32];
  __shared__ bf16 sB[128 * 32];

  const int tid = threadIdx.x;
  const int lane = tid & 63;
  const int wave = tid >> 6;
  const int wr = wave >> 1, wc = wave & 1;
  const int lr = lane & 15;
  const int lk = (lane >> 4) * 8;

  const bf16* At = A + (long)z * strA + (long)row * 128 * K;
  const bf16* Bt = B + (long)z * strB + (long)col * 128 * K;

  f32x4 acc[4][4] = {};

  for (int k0 = 0; k0 < K; k0 += 32) {
#pragma unroll
    for (int h = 0; h < 2; ++h) {
      const int c = tid + h * 256;
      const int r = c >> 2;
      const int cc = (c & 3) * 8;
      GLOAD16(At + (long)r * K + k0 + cc, (char*)sA + c * 16);
      GLOAD16(Bt + (long)r * K + k0 + cc, (char*)sB + c * 16);
    }
    __syncthreads();

    bf16x8 af[4], bfr[4];
#pragma unroll
    for (int m = 0; m < 4; ++m)
      af[m] = *reinterpret_cast<const bf16x8*>(&sA[(wr * 64 + m * 16 + lr) * 32 + lk]);
#pragma unroll
    for (int n = 0; n < 4; ++n)
      bfr[n] = *reinterpret_cast<const bf16x8*>(&sB[(wc * 64 + n * 16 + lr) * 32 + lk]);
#pragma unroll
    for (int m = 0; m < 4; ++m)
#pragma unroll
      for (int n = 0; n < 4; ++n)
        acc[m][n] = __builtin_amdgcn_mfma_f32_16x16x32_bf16(af[m], bfr[n], acc[m][n], 0, 0, 0);
    __syncthreads();
  }

  // epilogue: C/D layout col = lane&15, row = (lane>>4)*4 + j  [m89-verified]
  const int lg = (lane >> 4) * 4;
  OUT* Cb = C + (long)z * strC;
#pragma unroll
  for (int m = 0; m < 4; ++m) {
#pragma unroll
    for (int n = 0; n < 4; ++n) {
      const int gc = col * 128 + wc * 64 + n * 16 + lr;
      const float bv = bias ? bias[gc] : 0.0f;
#pragma unroll
      for (int j = 0; j < 4; ++j) {
        const int gr = row * 128 + wr * 64 + m * 16 + lg + j;
        Cb[(long)gr * N + gc] = (OUT)(acc[m][n][j] * scale + bv);
      }
    }
  }
}

// ---------------------------------------------------------------------------
// V projection with TRANSPOSED output: VT[b][h][s] = hs[b,s,:].WvT[h,:] + bv[h]
// Same GEMM body; epilogue exploits that acc[m][n][0..3] are 4 consecutive
// A-rows (s) of ONE column (h) -> contiguous bf16x4 in the [H][S] layout.
__global__ __launch_bounds__(256) void k_gemm_vt(const bf16* __restrict__ A,
                                                 const bf16* __restrict__ B,
                                                 bf16* __restrict__ VT,
                                                 const float* __restrict__ bias) {
  const int id = xcd_swz();   // grid 1536: 6 h-panels x 256 s-panels
  const int col = id % 6;
  const int row = id / 6;
  const int b = row >> 6;            // 64 s-panels per batch
  const int s0 = (row & 63) * 128;

  __shared__ bf16 sA[128 * 32];
  __shared__ bf16 sB[128 * 32];

  const int tid = threadIdx.x;
  const int lane = tid & 63;
  const int wave = tid >> 6;
  const int wr = wave >> 1, wc = wave & 1;
  const int lr = lane & 15;
  const int lk = (lane >> 4) * 8;

  const bf16* At = A + (long)row * 128 * HIDDEN;
  const bf16* Bt = B + (long)col * 128 * HIDDEN;

  f32x4 acc[4][4] = {};

  for (int k0 = 0; k0 < HIDDEN; k0 += 32) {
#pragma unroll
    for (int h = 0; h < 2; ++h) {
      const int c = tid + h * 256;
      const int r = c >> 2;
      const int cc = (c & 3) * 8;
      GLOAD16(At + (long)r * HIDDEN + k0 + cc, (char*)sA + c * 16);
      GLOAD16(Bt + (long)r * HIDDEN + k0 + cc, (char*)sB + c * 16);
    }
    __syncthreads();

    bf16x8 af[4], bfr[4];
#pragma unroll
    for (int m = 0; m < 4; ++m)
      af[m] = *reinterpret_cast<const bf16x8*>(&sA[(wr * 64 + m * 16 + lr) * 32 + lk]);
#pragma unroll
    for (int n = 0; n < 4; ++n)
      bfr[n] = *reinterpret_cast<const bf16x8*>(&sB[(wc * 64 + n * 16 + lr) * 32 + lk]);
#pragma unroll
    for (int m = 0; m < 4; ++m)
#pragma unroll
      for (int n = 0; n < 4; ++n)
        acc[m][n] = __builtin_amdgcn_mfma_f32_16x16x32_bf16(af[m], bfr[n], acc[m][n], 0, 0, 0);
    __syncthreads();
  }

  // transposed epilogue: VT[b][gh][s0 + wr*64 + m*16 + lg + j]
  const int lg = (lane >> 4) * 4;
  bf16* Vb = VT + (long)b * HIDDEN * SEQ;
#pragma unroll
  for (int n = 0; n < 4; ++n) {
    const int gh = col * 128 + wc * 64 + n * 16 + lr;
    const float bv = bias[gh];
    bf16* dst = Vb + (long)gh * SEQ + s0 + wr * 64 + lg;
#pragma unroll
    for (int m = 0; m < 4; ++m) {
      bf16x4 o;
#pragma unroll
      for (int j = 0; j < 4; ++j) o[j] = (bf16)(acc[m][n][j] + bv);
      *reinterpret_cast<bf16x4*>(dst + m * 16) = o;
    }
  }
}

// ---------------------------------------------------------------------------
// PV split-K partial GEMM: Cpart[kc,b,q,:] = P[b, q-tile, kc-chunk] . VT^T
#define PV_KS 4
#define PV_KC (SEQ / PV_KS)
__global__ __launch_bounds__(256) void k_gemm_pv(const bf16* __restrict__ P,
                                                 const bf16* __restrict__ VT,
                                                 float* __restrict__ Cp) {
  const int id = xcd_swz();
  const int col = id % 6;
  int r = id / 6;
  const int row = r % 8;
  r /= 8;
  const int b = r % 4;
  const int kc = r / 4;

  __shared__ bf16 sA[128 * 32];
  __shared__ bf16 sB[128 * 32];

  const int tid = threadIdx.x;
  const int lane = tid & 63;
  const int wave = tid >> 6;
  const int wr = wave >> 1, wc = wave & 1;
  const int lr = lane & 15;
  const int lk = (lane >> 4) * 8;

  const bf16* At = P + (long)b * NQ * SEQ + (long)row * 128 * SEQ + (long)kc * PV_KC;
  const bf16* Bt = VT + (long)b * HIDDEN * SEQ + (long)col * 128 * SEQ + (long)kc * PV_KC;

  f32x4 acc[4][4] = {};

  for (int k0 = 0; k0 < PV_KC; k0 += 32) {
#pragma unroll
    for (int h = 0; h < 2; ++h) {
      const int c = tid + h * 256;
      const int rr = c >> 2;
      const int cc = (c & 3) * 8;
      GLOAD16(At + (long)rr * SEQ + k0 + cc, (char*)sA + c * 16);
      GLOAD16(Bt + (long)rr * SEQ + k0 + cc, (char*)sB + c * 16);
    }
    __syncthreads();

    bf16x8 af[4], bfr[4];
#pragma unroll
    for (int m = 0; m < 4; ++m)
      af[m] = *reinterpret_cast<const bf16x8*>(&sA[(wr * 64 + m * 16 + lr) * 32 + lk]);
#pragma unroll
    for (int n = 0; n < 4; ++n)
      bfr[n] = *reinterpret_cast<const bf16x8*>(&sB[(wc * 64 + n * 16 + lr) * 32 + lk]);
#pragma unroll
    for (int m = 0; m < 4; ++m)
#pragma unroll
      for (int n = 0; n < 4; ++n)
        acc[m][n] = __builtin_amdgcn_mfma_f32_16x16x32_bf16(af[m], bfr[n], acc[m][n], 0, 0, 0);
    __syncthreads();
  }

  float* Co = Cp + ((long)kc * BATCH + b) * NQ * HIDDEN;
  const int lg = (lane >> 4) * 4;
#pragma unroll
  for (int m = 0; m < 4; ++m) {
#pragma unroll
    for (int n = 0; n < 4; ++n) {
      const int gc = col * 128 + wc * 64 + n * 16 + lr;
#pragma unroll
      for (int j = 0; j < 4; ++j) {
        const int gr = row * 128 + wr * 64 + m * 16 + lg + j;
        Co[(long)gr * HIDDEN + gc] = acc[m][n][j];
      }
    }
  }
}

// out = p0 + p1 + p2 + p3 (fp32, float4 vectorized)
__global__ __launch_bounds__(256) void k_reduce4(const float* __restrict__ p,
                                                 float* __restrict__ out, int n4) {
  const long NB = (long)BATCH * NQ * HIDDEN;
  const int stride = gridDim.x * blockDim.x;
  for (int i = blockIdx.x * blockDim.x + threadIdx.x; i < n4; i += stride) {
    f32x4 a = reinterpret_cast<const f32x4*>(p)[i];
    f32x4 b = reinterpret_cast<const f32x4*>(p + NB)[i];
    f32x4 c = reinterpret_cast<const f32x4*>(p + 2 * NB)[i];
    f32x4 d = reinterpret_cast<const f32x4*>(p + 3 * NB)[i];
    reinterpret_cast<f32x4*>(out)[i] = (a + b) + (c + d);
  }
}

// ---------------------------------------------------------------------------
// Row softmax over SEQ with additive mask bias, in-place on bf16 probs.
__global__ __launch_bounds__(256) void k_softmax(bf16* __restrict__ P,
                                                 const float* __restrict__ mask) {
  const int row = blockIdx.x;  // b * NQ + q
  bf16* p = P + (long)row * SEQ;
  const float* mrow = mask + (long)(row >> 10) * SEQ;
  const int t = threadIdx.x;

  float v[32];
  float mx = -3.0e38f;
#pragma unroll
  for (int c = 0; c < 4; ++c) {
    const int base = (c * 256 + t) * 8;
    bf16x8 raw = *reinterpret_cast<const bf16x8*>(p + base);
#pragma unroll
    for (int j = 0; j < 8; ++j) {
      const float mb = (1.0f - mrow[base + j]) * -10000.0f;
      const float s = (float)raw[j] + mb;
      v[c * 8 + j] = s;
      mx = fmaxf(mx, s);
    }
  }
#pragma unroll
  for (int o = 32; o > 0; o >>= 1) mx = fmaxf(mx, __shfl_xor(mx, o));
  __shared__ float redm[4];
  __shared__ float reds[4];
  const int wave = t >> 6, lane = t & 63;
  if (lane == 0) redm[wave] = mx;
  __syncthreads();
  mx = fmaxf(fmaxf(redm[0], redm[1]), fmaxf(redm[2], redm[3]));

  float sum = 0.0f;
#pragma unroll
  for (int i = 0; i < 32; ++i) {
    v[i] = expf(v[i] - mx);
    sum += v[i];
  }
#pragma unroll
  for (int o = 32; o > 0; o >>= 1) sum += __shfl_xor(sum, o);
  if (lane == 0) reds[wave] = sum;
  __syncthreads();
  sum = reds[0] + reds[1] + reds[2] + reds[3];
  const float inv = 1.0f / sum;

#pragma unroll
  for (int c = 0; c < 4; ++c) {
    const int base = (c * 256 + t) * 8;
    bf16x8 o;
#pragma unroll
    for (int j = 0; j < 8; ++j) o[j] = (bf16)(v[c * 8 + j] * inv);
    *reinterpret_cast<bf16x8*>(p + base) = o;
  }
}

// ---------------------------------------------------------------------------
extern "C" void kernel_launch(void* const* d_in, const int* in_sizes, int n_in,
                              void* d_out, int out_size, void* d_ws, size_t ws_size,
                              hipStream_t stream) {
  const float* hs = (const float*)d_in[0];    // [B,S,H]
  const float* qu = (const float*)d_in[1];    // [B,Q,H]
  const float* mask = (const float*)d_in[2];  // [B,S]
  const float* Wq = (const float*)d_in[3];
  const float* bq = (const float*)d_in[4];
  const float* Wk = (const float*)d_in[5];
  const float* bk = (const float*)d_in[6];
  const float* Wv = (const float*)d_in[7];
  const float* bv = (const float*)d_in[8];
  float* out = (float*)d_out;  // [B,Q,H] fp32

  const size_t HS_N = (size_t)BATCH * SEQ * HIDDEN;
  const size_t QU_N = (size_t)BATCH * NQ * HIDDEN;
  const size_t W_N = (size_t)HIDDEN * HIDDEN;
  const size_t P_N = (size_t)BATCH * NQ * SEQ;

  char* ws = (char*)d_ws;
  size_t off = 0;
  auto alloc = [&](size_t bytes) {
    char* p = ws + off;
    off += (bytes + 255) & ~(size_t)255;
    return p;
  };

  // region 0 (67.1 MB): probs (late) overlap hidden_bf16/queries_bf16/W^T (early)
  char* region0 = alloc(P_N * 2);
  bf16* Pr = (bf16*)region0;
  bf16* hsb = (bf16*)region0;
  bf16* qub = (bf16*)(region0 + HS_N * 2);
  bf16* WqT = (bf16*)(region0 + HS_N * 2 + QU_N * 2);
  bf16* WkT = WqT + W_N;
  bf16* WvT = WkT + W_N;

  char* kbRegion = alloc(HS_N * 2);  // Kb early; PV partials (50.33 MB) late
  bf16* Kb = (bf16*)kbRegion;
  float* Ppart = (float*)kbRegion;   // PV_KS * B*Q*H fp32 = 50,331,648 B exactly
  bf16* VT = (bf16*)alloc(HS_N * 2); // [B][H][S] bf16 (written directly by k_gemm_vt)
  bf16* Qb = (bf16*)alloc(QU_N * 2);

  // 1) converts
  k_cvt<<<dim3(2048), dim3(256), 0, stream>>>(hs, hsb, (int)(HS_N / 4));
  k_cvt<<<dim3(1024), dim3(256), 0, stream>>>(qu, qub, (int)(QU_N / 4));

  // 2) W transposes (fp32 -> bf16, [H][D] -> [D][H])
  k_transpose_w<<<dim3(24, 24), dim3(256), 0, stream>>>(Wq, WqT, HIDDEN, HIDDEN);
  k_transpose_w<<<dim3(24, 24), dim3(256), 0, stream>>>(Wk, WkT, HIDDEN, HIDDEN);
  k_transpose_w<<<dim3(24, 24), dim3(256), 0, stream>>>(Wv, WvT, HIDDEN, HIDDEN);

  // 3) projections: K (plain), V (transposed output), Q (plain)
  k_gemm_bt<bf16><<<dim3(1536), dim3(256), 0, stream>>>(
      hsb, WkT, Kb, bk, HIDDEN, HIDDEN, 1.0f, 6, 256, 0, 0, 0, 0);
  k_gemm_vt<<<dim3(1536), dim3(256), 0, stream>>>(hsb, WvT, VT, bv);
  k_gemm_bt<bf16><<<dim3(192), dim3(256), 0, stream>>>(
      qub, WqT, Qb, bq, HIDDEN, HIDDEN, 1.0f, 6, 32, 0, 0, 0, 0);

  // 4) scores: Pr[b] = Q[b].K[b]^T / sqrt(H)   (rowfast swizzle: Q-panels L2-resident)
  const float qkscale = 1.0f / sqrtf((float)HIDDEN);
  k_gemm_bt<bf16><<<dim3(2048), dim3(256), 0, stream>>>(
      Qb, Kb, Pr, nullptr, SEQ, HIDDEN, qkscale, 64, 8, 1,
      (long)NQ * HIDDEN, (long)SEQ * HIDDEN, (long)NQ * SEQ);

  // 5) softmax rows (in-place, with mask bias)
  k_softmax<<<dim3(BATCH * NQ), dim3(256), 0, stream>>>(Pr, mask);

  // 6) context partials + reduce
  k_gemm_pv<<<dim3(6 * 8 * 4 * PV_KS), dim3(256), 0, stream>>>(Pr, VT, Ppart);
  k_reduce4<<<dim3(1024), dim3(256), 0, stream>>>(Ppart, out, (int)(QU_N / 4));
}

// Round 4
// 362.341 us; speedup vs baseline: 1.3921x; 1.0497x over previous
//
#include <hip/hip_runtime.h>
#include <hip/hip_bf16.h>
#include <stdint.h>
#include <math.h>

#define HIDDEN 768
#define BATCH 4
#define SEQ 8192
#define NQ 1024

typedef __bf16 bf16;
typedef __bf16 bf16x4 __attribute__((ext_vector_type(4)));
typedef __bf16 bf16x8 __attribute__((ext_vector_type(8)));
typedef float f32x4 __attribute__((ext_vector_type(4)));

// Bijective XCD-chunked block-id swizzle (requires gridDim.x % 8 == 0).
__device__ inline int xcd_swz() {
  const int o = blockIdx.x;
  const int chunk = gridDim.x >> 3;
  return (o & 7) * chunk + (o >> 3);
}

// ---------------------------------------------------------------------------
// fp32 -> bf16 elementwise convert (float4 vectorized, grid-stride)
__global__ __launch_bounds__(256) void k_cvt(const float* __restrict__ in,
                                             bf16* __restrict__ out, int n4) {
  int stride = gridDim.x * blockDim.x;
  for (int i = blockIdx.x * blockDim.x + threadIdx.x; i < n4; i += stride) {
    float4 v = reinterpret_cast<const float4*>(in)[i];
    bf16x4 o = {(bf16)v.x, (bf16)v.y, (bf16)v.z, (bf16)v.w};
    reinterpret_cast<bf16x4*>(out)[i] = o;
  }
}

// ---------------------------------------------------------------------------
// [R][C] fp32 -> [C][R] bf16 tiled transpose-convert (weights).
__global__ __launch_bounds__(256) void k_transpose_w(
    const float* __restrict__ in, bf16* __restrict__ out, int R, int C) {
  __shared__ float tile[32][33];
  const int c0 = blockIdx.x * 32, r0 = blockIdx.y * 32;
  const int tx = threadIdx.x & 31, ty = threadIdx.x >> 5;  // 32 x 8
#pragma unroll
  for (int i = 0; i < 32; i += 8)
    tile[ty + i][tx] = in[(long)(r0 + ty + i) * C + (c0 + tx)];
  __syncthreads();
#pragma unroll
  for (int i = 0; i < 32; i += 8)
    out[(long)(c0 + ty + i) * R + (r0 + tx)] = (bf16)tile[tx][ty + i];
}

// ---------------------------------------------------------------------------
// [R][C] bf16 -> [C][R] bf16 batched tiled transpose (for hs^T).
__global__ __launch_bounds__(256) void k_transpose_b(
    const bf16* __restrict__ in, bf16* __restrict__ out, int R, int C,
    long inBatchStride, long outBatchStride) {
  __shared__ float tile[32][33];
  const long bIn = (long)blockIdx.z * inBatchStride;
  const long bOut = (long)blockIdx.z * outBatchStride;
  const int c0 = blockIdx.x * 32, r0 = blockIdx.y * 32;
  const int tx = threadIdx.x & 31, ty = threadIdx.x >> 5;
#pragma unroll
  for (int i = 0; i < 32; i += 8)
    tile[ty + i][tx] = (float)in[bIn + (long)(r0 + ty + i) * C + (c0 + tx)];
  __syncthreads();
#pragma unroll
  for (int i = 0; i < 32; i += 8)
    out[bOut + (long)(c0 + ty + i) * R + (r0 + tx)] = (bf16)tile[tx][ty + i];
}

#define GLOAD16(gptr, lptr)                                                   \
  __builtin_amdgcn_global_load_lds(                                           \
      (const __attribute__((address_space(1))) void*)(gptr),                  \
      (__attribute__((address_space(3))) void*)(lptr), 16, 0, 0)

// ---------------------------------------------------------------------------
// C[M,N] = (A[M,K] . B[N,K]^T) * scale + bias[col]
// m97 structure: 128x128 tile, BK=32, 4 waves (2x2 of 64x64), 16x16x32 MFMA,
// global_load_lds width 16. 1-D grid with XCD-chunked swizzle.
template <typename OUT>
__global__ __launch_bounds__(256) void k_gemm_bt(
    const bf16* __restrict__ A, const bf16* __restrict__ B, OUT* __restrict__ C,
    const float* __restrict__ bias, int N, int K, float scale,
    int nx, int ny, int rowfast, long strA, long strB, long strC) {
  const int id = xcd_swz();
  int col, row, z;
  if (rowfast) {
    row = id % ny; col = (id / ny) % nx; z = id / (ny * nx);
  } else {
    col = id % nx; row = (id / nx) % ny; z = id / (nx * ny);
  }

  __shared__ bf16 sA[128 * 32];
  __shared__ bf16 sB[128 * 32];

  const int tid = threadIdx.x;
  const int lane = tid & 63;
  const int wave = tid >> 6;
  const int wr = wave >> 1, wc = wave & 1;
  const int lr = lane & 15;
  const int lk = (lane >> 4) * 8;

  const bf16* At = A + (long)z * strA + (long)row * 128 * K;
  const bf16* Bt = B + (long)z * strB + (long)col * 128 * K;

  f32x4 acc[4][4] = {};

  for (int k0 = 0; k0 < K; k0 += 32) {
#pragma unroll
    for (int h = 0; h < 2; ++h) {
      const int c = tid + h * 256;
      const int r = c >> 2;
      const int cc = (c & 3) * 8;
      GLOAD16(At + (long)r * K + k0 + cc, (char*)sA + c * 16);
      GLOAD16(Bt + (long)r * K + k0 + cc, (char*)sB + c * 16);
    }
    __syncthreads();

    bf16x8 af[4], bfr[4];
#pragma unroll
    for (int m = 0; m < 4; ++m)
      af[m] = *reinterpret_cast<const bf16x8*>(&sA[(wr * 64 + m * 16 + lr) * 32 + lk]);
#pragma unroll
    for (int n = 0; n < 4; ++n)
      bfr[n] = *reinterpret_cast<const bf16x8*>(&sB[(wc * 64 + n * 16 + lr) * 32 + lk]);
#pragma unroll
    for (int m = 0; m < 4; ++m)
#pragma unroll
      for (int n = 0; n < 4; ++n)
        acc[m][n] = __builtin_amdgcn_mfma_f32_16x16x32_bf16(af[m], bfr[n], acc[m][n], 0, 0, 0);
    __syncthreads();
  }

  // epilogue: C/D layout col = lane&15, row = (lane>>4)*4 + j  [m89-verified]
  const int lg = (lane >> 4) * 4;
  OUT* Cb = C + (long)z * strC;
#pragma unroll
  for (int m = 0; m < 4; ++m) {
#pragma unroll
    for (int n = 0; n < 4; ++n) {
      const int gc = col * 128 + wc * 64 + n * 16 + lr;
      const float bv = bias ? bias[gc] : 0.0f;
#pragma unroll
      for (int j = 0; j < 4; ++j) {
        const int gr = row * 128 + wr * 64 + m * 16 + lg + j;
        Cb[(long)gr * N + gc] = (OUT)(acc[m][n][j] * scale + bv);
      }
    }
  }
}

// ---------------------------------------------------------------------------
// PHS split-K partial GEMM: Cpart[kc][b,q,:] = P[b, q-tile, kc-chunk] . hsT^T
// P: [B][NQ][SEQ] bf16, hsT: [B][HIDDEN][SEQ] bf16, partials bf16.
// KS=8 chunks of 1024 -> 1536 blocks -> ~6 blocks/CU (latency hiding).
#define PHS_KS 8
#define PHS_KC (SEQ / PHS_KS)
__global__ __launch_bounds__(256, 5) void k_gemm_phs(const bf16* __restrict__ P,
                                                     const bf16* __restrict__ HT,
                                                     bf16* __restrict__ Cp) {
  const int id = xcd_swz();
  const int col = id % 6;
  int r = id / 6;
  const int row = r % 8;
  r /= 8;
  const int b = r % 4;
  const int kc = r / 4;

  __shared__ bf16 sA[128 * 32];
  __shared__ bf16 sB[128 * 32];

  const int tid = threadIdx.x;
  const int lane = tid & 63;
  const int wave = tid >> 6;
  const int wr = wave >> 1, wc = wave & 1;
  const int lr = lane & 15;
  const int lk = (lane >> 4) * 8;

  const bf16* At = P + (long)b * NQ * SEQ + (long)row * 128 * SEQ + (long)kc * PHS_KC;
  const bf16* Bt = HT + (long)b * HIDDEN * SEQ + (long)col * 128 * SEQ + (long)kc * PHS_KC;

  f32x4 acc[4][4] = {};

  for (int k0 = 0; k0 < PHS_KC; k0 += 32) {
#pragma unroll
    for (int h = 0; h < 2; ++h) {
      const int c = tid + h * 256;
      const int rr = c >> 2;
      const int cc = (c & 3) * 8;
      GLOAD16(At + (long)rr * SEQ + k0 + cc, (char*)sA + c * 16);
      GLOAD16(Bt + (long)rr * SEQ + k0 + cc, (char*)sB + c * 16);
    }
    __syncthreads();

    bf16x8 af[4], bfr[4];
#pragma unroll
    for (int m = 0; m < 4; ++m)
      af[m] = *reinterpret_cast<const bf16x8*>(&sA[(wr * 64 + m * 16 + lr) * 32 + lk]);
#pragma unroll
    for (int n = 0; n < 4; ++n)
      bfr[n] = *reinterpret_cast<const bf16x8*>(&sB[(wc * 64 + n * 16 + lr) * 32 + lk]);
#pragma unroll
    for (int m = 0; m < 4; ++m)
#pragma unroll
      for (int n = 0; n < 4; ++n)
        acc[m][n] = __builtin_amdgcn_mfma_f32_16x16x32_bf16(af[m], bfr[n], acc[m][n], 0, 0, 0);
    __syncthreads();
  }

  bf16* Co = Cp + ((long)kc * BATCH + b) * NQ * HIDDEN;
  const int lg = (lane >> 4) * 4;
#pragma unroll
  for (int m = 0; m < 4; ++m) {
#pragma unroll
    for (int n = 0; n < 4; ++n) {
      const int gc = col * 128 + wc * 64 + n * 16 + lr;
#pragma unroll
      for (int j = 0; j < 4; ++j) {
        const int gr = row * 128 + wr * 64 + m * 16 + lg + j;
        Co[(long)gr * HIDDEN + gc] = (bf16)acc[m][n][j];
      }
    }
  }
}

// ctx1 = sum of 8 bf16 partials (fp32 accumulate, bf16 out)
__global__ __launch_bounds__(256) void k_reduce8(const bf16* __restrict__ p,
                                                 bf16* __restrict__ out, int n8) {
  const long NB = (long)BATCH * NQ * HIDDEN;
  const int stride = gridDim.x * blockDim.x;
  for (int i = blockIdx.x * blockDim.x + threadIdx.x; i < n8; i += stride) {
    float acc[8] = {};
#pragma unroll
    for (int k = 0; k < PHS_KS; ++k) {
      bf16x8 v = reinterpret_cast<const bf16x8*>(p + k * NB)[i];
#pragma unroll
      for (int j = 0; j < 8; ++j) acc[j] += (float)v[j];
    }
    bf16x8 o;
#pragma unroll
    for (int j = 0; j < 8; ++j) o[j] = (bf16)acc[j];
    reinterpret_cast<bf16x8*>(out)[i] = o;
  }
}

// ---------------------------------------------------------------------------
// Row softmax over SEQ with additive mask bias, in-place on bf16 probs.
__global__ __launch_bounds__(256) void k_softmax(bf16* __restrict__ P,
                                                 const float* __restrict__ mask) {
  const int row = blockIdx.x;  // b * NQ + q
  bf16* p = P + (long)row * SEQ;
  const float* mrow = mask + (long)(row >> 10) * SEQ;
  const int t = threadIdx.x;

  float v[32];
  float mx = -3.0e38f;
#pragma unroll
  for (int c = 0; c < 4; ++c) {
    const int base = (c * 256 + t) * 8;
    bf16x8 raw = *reinterpret_cast<const bf16x8*>(p + base);
#pragma unroll
    for (int j = 0; j < 8; ++j) {
      const float mb = (1.0f - mrow[base + j]) * -10000.0f;
      const float s = (float)raw[j] + mb;
      v[c * 8 + j] = s;
      mx = fmaxf(mx, s);
    }
  }
#pragma unroll
  for (int o = 32; o > 0; o >>= 1) mx = fmaxf(mx, __shfl_xor(mx, o));
  __shared__ float redm[4];
  __shared__ float reds[4];
  const int wave = t >> 6, lane = t & 63;
  if (lane == 0) redm[wave] = mx;
  __syncthreads();
  mx = fmaxf(fmaxf(redm[0], redm[1]), fmaxf(redm[2], redm[3]));

  float sum = 0.0f;
#pragma unroll
  for (int i = 0; i < 32; ++i) {
    v[i] = expf(v[i] - mx);
    sum += v[i];
  }
#pragma unroll
  for (int o = 32; o > 0; o >>= 1) sum += __shfl_xor(sum, o);
  if (lane == 0) reds[wave] = sum;
  __syncthreads();
  sum = reds[0] + reds[1] + reds[2] + reds[3];
  const float inv = 1.0f / sum;

#pragma unroll
  for (int c = 0; c < 4; ++c) {
    const int base = (c * 256 + t) * 8;
    bf16x8 o;
#pragma unroll
    for (int j = 0; j < 8; ++j) o[j] = (bf16)(v[c * 8 + j] * inv);
    *reinterpret_cast<bf16x8*>(p + base) = o;
  }
}

// ---------------------------------------------------------------------------
extern "C" void kernel_launch(void* const* d_in, const int* in_sizes, int n_in,
                              void* d_out, int out_size, void* d_ws, size_t ws_size,
                              hipStream_t stream) {
  const float* hs = (const float*)d_in[0];    // [B,S,H]
  const float* qu = (const float*)d_in[1];    // [B,Q,H]
  const float* mask = (const float*)d_in[2];  // [B,S]
  const float* Wq = (const float*)d_in[3];
  const float* bq = (const float*)d_in[4];
  const float* Wk = (const float*)d_in[5];
  const float* bv = (const float*)d_in[8];
  const float* Wv = (const float*)d_in[7];
  float* out = (float*)d_out;  // [B,Q,H] fp32
  // note: bk (d_in[6]) contributes only a softmax-row-constant -> drops out.

  const size_t HS_N = (size_t)BATCH * SEQ * HIDDEN;   // 25,165,824
  const size_t QU_N = (size_t)BATCH * NQ * HIDDEN;    //  3,145,728
  const size_t W_N = (size_t)HIDDEN * HIDDEN;         //    589,824
  const size_t P_N = (size_t)BATCH * NQ * SEQ;        // 33,554,432

  char* ws = (char*)d_ws;
  size_t off = 0;
  auto alloc = [&](size_t bytes) {
    char* p = ws + off;
    off += (bytes + 255) & ~(size_t)255;
    return p;
  };

  // region A (50.33 MB): hsb early / PHS partials (8 x QU_N bf16 = same size) late
  char* regionA = alloc(HS_N * 2);
  bf16* hsb = (bf16*)regionA;
  bf16* Ppart = (bf16*)regionA;  // PHS_KS * QU_N * 2 = HS_N * 2 exactly
  bf16* hsT = (bf16*)alloc(HS_N * 2);   // [B][H][S]
  bf16* Pr = (bf16*)alloc(P_N * 2);     // scores/probs
  char* regionD0 = alloc(QU_N * 2);     // qub early / tmpb late
  bf16* qub = (bf16*)regionD0;
  bf16* tmpb = (bf16*)regionD0;
  char* regionD1 = alloc(QU_N * 2);     // Qb early / ctx1 late
  bf16* Qb = (bf16*)regionD1;
  bf16* ctx1 = (bf16*)regionD1;
  bf16* WqT = (bf16*)alloc(W_N * 2);
  bf16* Wkb = (bf16*)alloc(W_N * 2);
  bf16* WvT = (bf16*)alloc(W_N * 2);

  // 1) converts
  k_cvt<<<dim3(2048), dim3(256), 0, stream>>>(hs, hsb, (int)(HS_N / 4));
  k_cvt<<<dim3(1024), dim3(256), 0, stream>>>(qu, qub, (int)(QU_N / 4));
  k_cvt<<<dim3(576), dim3(256), 0, stream>>>(Wk, Wkb, (int)(W_N / 4));

  // 2) weight transposes
  k_transpose_w<<<dim3(24, 24), dim3(256), 0, stream>>>(Wq, WqT, HIDDEN, HIDDEN);
  k_transpose_w<<<dim3(24, 24), dim3(256), 0, stream>>>(Wv, WvT, HIDDEN, HIDDEN);

  // 3) hs^T per batch: [S][H] -> [H][S]
  k_transpose_b<<<dim3(24, 256, 4), dim3(256), 0, stream>>>(
      hsb, hsT, SEQ, HIDDEN, (long)SEQ * HIDDEN, (long)HIDDEN * SEQ);

  // 4) Q projection: Qb = qu.Wq + bq
  k_gemm_bt<bf16><<<dim3(192), dim3(256), 0, stream>>>(
      qub, WqT, Qb, bq, HIDDEN, HIDDEN, 1.0f, 6, 32, 0, 0, 0, 0);

  // 5) K-fold: tmp[i,h] = sum_d Wk[h,d] * Q[i,d]   (B = Wk row-major, no transpose)
  k_gemm_bt<bf16><<<dim3(192), dim3(256), 0, stream>>>(
      Qb, Wkb, tmpb, nullptr, HIDDEN, HIDDEN, 1.0f, 6, 32, 0, 0, 0, 0);

  // 6) scores: Pr[b] = tmp[b].hsb[b]^T / sqrt(H)   (q.bk row-constant cancels)
  const float qkscale = 1.0f / sqrtf((float)HIDDEN);
  k_gemm_bt<bf16><<<dim3(2048), dim3(256), 0, stream>>>(
      tmpb, hsb, Pr, nullptr, SEQ, HIDDEN, qkscale, 64, 8, 1,
      (long)NQ * HIDDEN, (long)SEQ * HIDDEN, (long)NQ * SEQ);

  // 7) softmax rows (in-place, with mask bias)
  k_softmax<<<dim3(BATCH * NQ), dim3(256), 0, stream>>>(Pr, mask);

  // 8) PHS partials: Ppart[kc] = P[:, kc-chunk] . hsT^T   (overwrites hsb - dead)
  k_gemm_phs<<<dim3(6 * 8 * 4 * PHS_KS), dim3(256), 0, stream>>>(Pr, hsT, Ppart);

  // 9) reduce partials -> ctx1 = P.hs  (bf16)
  k_reduce8<<<dim3(1536), dim3(256), 0, stream>>>(Ppart, ctx1, (int)(QU_N / 8));

  // 10) V-fold: out = ctx1.Wv + bv  (sum_j p = 1 makes +bv exact)
  k_gemm_bt<float><<<dim3(192), dim3(256), 0, stream>>>(
      ctx1, WvT, out, bv, HIDDEN, HIDDEN, 1.0f, 6, 32, 0, 0, 0, 0);
}

// Round 5
// 268.441 us; speedup vs baseline: 1.8791x; 1.3498x over previous
//
#include <hip/hip_runtime.h>
#include <hip/hip_bf16.h>
#include <stdint.h>
#include <math.h>

#define HIDDEN 768
#define BATCH 4
#define SEQ 8192
#define NQ 1024

typedef __bf16 bf16;
typedef __bf16 bf16x4 __attribute__((ext_vector_type(4)));
typedef __bf16 bf16x8 __attribute__((ext_vector_type(8)));
typedef float f32x4 __attribute__((ext_vector_type(4)));

// General bijective XCD-chunked block-id swizzle (m204 formula, any grid size).
__device__ inline int xcd_swz() {
  const unsigned n = gridDim.x, o = blockIdx.x;
  const unsigned q = n >> 3, r = n & 7;
  const unsigned x = o & 7, k = o >> 3;
  return (int)((x < r ? x * (q + 1) : r * (q + 1) + (x - r) * q) + k);
}

#define GLOAD16(gptr, lptr)                                                   \
  __builtin_amdgcn_global_load_lds(                                           \
      (const __attribute__((address_space(1))) void*)(gptr),                  \
      (__attribute__((address_space(3))) void*)(lptr), 16, 0, 0)

// ---------------------------------------------------------------------------
// fp32 -> bf16 elementwise convert (float4 vectorized, grid-stride)
__global__ __launch_bounds__(256) void k_cvt(const float* __restrict__ in,
                                             bf16* __restrict__ out, int n4) {
  int stride = gridDim.x * blockDim.x;
  for (int i = blockIdx.x * blockDim.x + threadIdx.x; i < n4; i += stride) {
    float4 v = reinterpret_cast<const float4*>(in)[i];
    bf16x4 o = {(bf16)v.x, (bf16)v.y, (bf16)v.z, (bf16)v.w};
    reinterpret_cast<bf16x4*>(out)[i] = o;
  }
}

// ---------------------------------------------------------------------------
// [R][C] fp32 -> [C][R] bf16 tiled transpose-convert (weights).
__global__ __launch_bounds__(256) void k_transpose_w(
    const float* __restrict__ in, bf16* __restrict__ out, int R, int C) {
  __shared__ float tile[32][33];
  const int c0 = blockIdx.x * 32, r0 = blockIdx.y * 32;
  const int tx = threadIdx.x & 31, ty = threadIdx.x >> 5;  // 32 x 8
#pragma unroll
  for (int i = 0; i < 32; i += 8)
    tile[ty + i][tx] = in[(long)(r0 + ty + i) * C + (c0 + tx)];
  __syncthreads();
#pragma unroll
  for (int i = 0; i < 32; i += 8)
    out[(long)(c0 + ty + i) * R + (r0 + tx)] = (bf16)tile[tx][ty + i];
}

// ---------------------------------------------------------------------------
// Fused: hs fp32 [B*S][H] -> hsb bf16 (same layout) + hsT bf16 [B][H][S].
// Tile: 32 s-rows x 64 h-cols. One pass over the fp32 input.
__global__ __launch_bounds__(256) void k_cvt_hs_dual(const float* __restrict__ hs,
                                                     bf16* __restrict__ hsb,
                                                     bf16* __restrict__ hsT) {
  __shared__ float T[32][65];
  const int h0 = blockIdx.x * 64;
  const int s0g = blockIdx.y * 32;  // global row in [0, B*S)
  const int b = s0g >> 13;          // / 8192
  const int sIn = s0g & 8191;
  const int t = threadIdx.x;
  const int r = t >> 3, c = (t & 7) * 8;

  const float* src = hs + (long)(s0g + r) * HIDDEN + h0 + c;
  float4 v0 = *reinterpret_cast<const float4*>(src);
  float4 v1 = *reinterpret_cast<const float4*>(src + 4);
  T[r][c + 0] = v0.x; T[r][c + 1] = v0.y; T[r][c + 2] = v0.z; T[r][c + 3] = v0.w;
  T[r][c + 4] = v1.x; T[r][c + 5] = v1.y; T[r][c + 6] = v1.z; T[r][c + 7] = v1.w;

  bf16x8 o = {(bf16)v0.x, (bf16)v0.y, (bf16)v0.z, (bf16)v0.w,
              (bf16)v1.x, (bf16)v1.y, (bf16)v1.z, (bf16)v1.w};
  *reinterpret_cast<bf16x8*>(hsb + (long)(s0g + r) * HIDDEN + h0 + c) = o;

  __syncthreads();
  const int hh = t >> 2, ss = (t & 3) * 8;
  bf16x8 o2;
#pragma unroll
  for (int k = 0; k < 8; ++k) o2[k] = (bf16)T[ss + k][hh];
  *reinterpret_cast<bf16x8*>(hsT + ((long)b * HIDDEN + h0 + hh) * SEQ + sIn + ss) = o2;
}

// ---------------------------------------------------------------------------
// mbias = (1 - mask) * -10000  (float4 vectorized)
__global__ __launch_bounds__(256) void k_mbias(const float* __restrict__ mask,
                                               float* __restrict__ mb, int n4) {
  const int i = blockIdx.x * 256 + threadIdx.x;
  if (i < n4) {
    float4 m = reinterpret_cast<const float4*>(mask)[i];
    float4 o = {(1.0f - m.x) * -10000.0f, (1.0f - m.y) * -10000.0f,
                (1.0f - m.z) * -10000.0f, (1.0f - m.w) * -10000.0f};
    reinterpret_cast<float4*>(mb)[i] = o;
  }
}

// bqk[h] = sum_d bq[d] * Wk[h][d]   (one 64-thread block per h)
__global__ __launch_bounds__(64) void k_gemv_bqk(const float* __restrict__ Wk,
                                                 const float* __restrict__ bq,
                                                 float* __restrict__ bqk) {
  const int h = blockIdx.x, l = threadIdx.x;
  float s = 0.0f;
#pragma unroll
  for (int d = l; d < HIDDEN; d += 64) s += bq[d] * Wk[(long)h * HIDDEN + d];
#pragma unroll
  for (int o = 32; o > 0; o >>= 1) s += __shfl_xor(s, o);
  if (l == 0) bqk[h] = s;
}

// ---------------------------------------------------------------------------
// C[M,N] = (A[M,K].B[N,K]^T)*scale + bias[col]      (MODE 0)
//        = exp((A.B^T)*scale + mbias[z][col])       (MODE 1, bf16 out, + rowsums)
// 128x128 tile, BK=32, 4 waves, 16x16x32 MFMA, global_load_lds w16,
// DOUBLE-BUFFERED 2-phase K-loop (stage next before compute, 1 barrier/step),
// LDS-bounced coalesced C-writes for bf16 outputs.
template <typename OUT, int MODE>
__global__ __launch_bounds__(256) void k_gemm_bt(
    const bf16* __restrict__ A, const bf16* __restrict__ B, OUT* __restrict__ C,
    const float* __restrict__ bias, const float* __restrict__ mbias,
    float* __restrict__ rspart, int N, int K, float scale,
    int nx, int ny, int rowfast, long strA, long strB, long strC) {
  const int id = xcd_swz();
  int col, row, z;
  if (rowfast) {
    row = id % ny; col = (id / ny) % nx; z = id / (ny * nx);
  } else {
    col = id % nx; row = (id / nx) % ny; z = id / (nx * ny);
  }

  __shared__ bf16 smem[16384];  // [0,8K): A dbuf, [8K,16K): B dbuf; epilogue: C tile

  const int tid = threadIdx.x;
  const int lane = tid & 63, wave = tid >> 6;
  const int wr = wave >> 1, wc = wave & 1;
  const int lr = lane & 15, lk = (lane >> 4) * 8, lg = (lane >> 4) * 4;

  const bf16* At = A + (long)z * strA + (long)row * 128 * K;
  const bf16* Bt = B + (long)z * strB + (long)col * 128 * K;

#define STAGE_TILE(buf, k0)                                                   \
  {                                                                           \
    bf16* dA = smem + (buf) * 4096;                                           \
    bf16* dB = smem + 8192 + (buf) * 4096;                                    \
    _Pragma("unroll") for (int h = 0; h < 2; ++h) {                           \
      const int cch = tid + h * 256;                                          \
      const int rr = cch >> 2, cc = (cch & 3) * 8;                            \
      GLOAD16(At + (long)rr * K + (k0) + cc, (char*)dA + cch * 16);           \
      GLOAD16(Bt + (long)rr * K + (k0) + cc, (char*)dB + cch * 16);           \
    }                                                                         \
  }

  STAGE_TILE(0, 0);
  __syncthreads();

  f32x4 acc[4][4] = {};
  const int nt = K / 32;
  int cur = 0;
  for (int t = 0; t < nt; ++t) {
    if (t + 1 < nt) STAGE_TILE(cur ^ 1, (t + 1) * 32);
    const bf16* rA = smem + cur * 4096;
    const bf16* rB = smem + 8192 + cur * 4096;
    bf16x8 af[4], bfr[4];
#pragma unroll
    for (int m = 0; m < 4; ++m)
      af[m] = *reinterpret_cast<const bf16x8*>(&rA[(wr * 64 + m * 16 + lr) * 32 + lk]);
#pragma unroll
    for (int n = 0; n < 4; ++n)
      bfr[n] = *reinterpret_cast<const bf16x8*>(&rB[(wc * 64 + n * 16 + lr) * 32 + lk]);
#pragma unroll
    for (int m = 0; m < 4; ++m)
#pragma unroll
      for (int n = 0; n < 4; ++n)
        acc[m][n] = __builtin_amdgcn_mfma_f32_16x16x32_bf16(af[m], bfr[n], acc[m][n], 0, 0, 0);
    __syncthreads();
    cur ^= 1;
  }
#undef STAGE_TILE

  if constexpr (__is_same(OUT, float)) {
    // direct fp32 stores (64B segments, no amplification)
    float* Cb = (float*)C + (long)z * strC;
#pragma unroll
    for (int m = 0; m < 4; ++m)
#pragma unroll
      for (int n = 0; n < 4; ++n) {
        const int gc = col * 128 + wc * 64 + n * 16 + lr;
        const float bv = bias ? bias[gc] : 0.0f;
#pragma unroll
        for (int j = 0; j < 4; ++j) {
          const int gr = row * 128 + wr * 64 + m * 16 + lg + j;
          Cb[(long)gr * N + gc] = acc[m][n][j] * scale + bv;
        }
      }
  } else {
    // scatter to LDS (C/D layout: col=lane&15, row=(lane>>4)*4+j [m89]), then
    // linear 16B/lane coalesced copy-out.
    float rsv[4][4];
    if constexpr (MODE == 1) {
#pragma unroll
      for (int m = 0; m < 4; ++m)
#pragma unroll
        for (int j = 0; j < 4; ++j) rsv[m][j] = 0.0f;
    }
#pragma unroll
    for (int m = 0; m < 4; ++m)
#pragma unroll
      for (int n = 0; n < 4; ++n) {
        const int gc = col * 128 + wc * 64 + n * 16 + lr;
        float bv = 0.0f, mbv = 0.0f;
        if constexpr (MODE == 0) bv = bias ? bias[gc] : 0.0f;
        if constexpr (MODE == 1) mbv = mbias[(long)z * SEQ + gc];
#pragma unroll
        for (int j = 0; j < 4; ++j) {
          float v = acc[m][n][j] * scale;
          if constexpr (MODE == 1) {
            v = expf(v + mbv);
            rsv[m][j] += v;
          } else {
            v += bv;
          }
          smem[(wr * 64 + m * 16 + lg + j) * 128 + wc * 64 + n * 16 + lr] = (bf16)v;
        }
      }
    if constexpr (MODE == 1) {
      // per-row partial sums over this wave's 64 cols -> unique slot (no atomics)
#pragma unroll
      for (int m = 0; m < 4; ++m)
#pragma unroll
        for (int j = 0; j < 4; ++j) {
          float v = rsv[m][j];
          v += __shfl_xor(v, 1); v += __shfl_xor(v, 2);
          v += __shfl_xor(v, 4); v += __shfl_xor(v, 8);
          if ((lane & 15) == 0) {
            const int gr = row * 128 + wr * 64 + m * 16 + lg + j;
            rspart[((long)z * NQ + gr) * 128 + col * 2 + wc] = v;
          }
        }
    }
    __syncthreads();
    OUT* Cb = C + (long)z * strC;
    const long rb = (long)row * 128, cb = (long)col * 128;
#pragma unroll
    for (int i = 0; i < 8; ++i) {
      const int ch = tid + i * 256;     // 2048 chunks of 16B
      const int rr = ch >> 4;           // 16 chunks per 128-col row
      const int ce = (ch & 15) * 8;
      *reinterpret_cast<bf16x8*>(&Cb[(rb + rr) * N + cb + ce]) =
          *reinterpret_cast<const bf16x8*>(smem + ch * 8);
    }
  }
}

// rowsum[row] = sum of 128 partial slots (deterministic reduce)
__global__ __launch_bounds__(256) void k_rowsum(const float* __restrict__ rp,
                                                float* __restrict__ rs) {
  const int t = threadIdx.x;
  const int row = blockIdx.x * 8 + (t >> 5);
  const int s = t & 31;
  const float* base = rp + (long)row * 128;
  float v = base[s] + base[s + 32] + base[s + 64] + base[s + 96];
  v += __shfl_xor(v, 1); v += __shfl_xor(v, 2); v += __shfl_xor(v, 4);
  v += __shfl_xor(v, 8); v += __shfl_xor(v, 16);
  if (s == 0) rs[row] = v;
}

// ---------------------------------------------------------------------------
// PHS split-K partial GEMM: Cpart[kc][b,q,:] = P[b, q-tile, kc-chunk] . hsT^T
// Same dbuf 2-phase structure + LDS-bounced bf16 writes.
#define PHS_KS 8
#define PHS_KC (SEQ / PHS_KS)
__global__ __launch_bounds__(256) void k_gemm_phs(const bf16* __restrict__ P,
                                                  const bf16* __restrict__ HT,
                                                  bf16* __restrict__ Cp) {
  const int id = xcd_swz();
  const int col = id % 6;
  int r = id / 6;
  const int row = r % 8;
  r /= 8;
  const int b = r % 4;
  const int kc = r / 4;

  __shared__ bf16 smem[16384];

  const int tid = threadIdx.x;
  const int lane = tid & 63, wave = tid >> 6;
  const int wr = wave >> 1, wc = wave & 1;
  const int lr = lane & 15, lk = (lane >> 4) * 8, lg = (lane >> 4) * 4;

  const bf16* At = P + (long)b * NQ * SEQ + (long)row * 128 * SEQ + (long)kc * PHS_KC;
  const bf16* Bt = HT + (long)b * HIDDEN * SEQ + (long)col * 128 * SEQ + (long)kc * PHS_KC;

#define STAGE_PHS(buf, k0)                                                    \
  {                                                                           \
    bf16* dA = smem + (buf) * 4096;                                           \
    bf16* dB = smem + 8192 + (buf) * 4096;                                    \
    _Pragma("unroll") for (int h = 0; h < 2; ++h) {                           \
      const int cch = tid + h * 256;                                          \
      const int rr = cch >> 2, cc = (cch & 3) * 8;                            \
      GLOAD16(At + (long)rr * SEQ + (k0) + cc, (char*)dA + cch * 16);         \
      GLOAD16(Bt + (long)rr * SEQ + (k0) + cc, (char*)dB + cch * 16);         \
    }                                                                         \
  }

  STAGE_PHS(0, 0);
  __syncthreads();

  f32x4 acc[4][4] = {};
  const int nt = PHS_KC / 32;
  int cur = 0;
  for (int t = 0; t < nt; ++t) {
    if (t + 1 < nt) STAGE_PHS(cur ^ 1, (t + 1) * 32);
    const bf16* rA = smem + cur * 4096;
    const bf16* rB = smem + 8192 + cur * 4096;
    bf16x8 af[4], bfr[4];
#pragma unroll
    for (int m = 0; m < 4; ++m)
      af[m] = *reinterpret_cast<const bf16x8*>(&rA[(wr * 64 + m * 16 + lr) * 32 + lk]);
#pragma unroll
    for (int n = 0; n < 4; ++n)
      bfr[n] = *reinterpret_cast<const bf16x8*>(&rB[(wc * 64 + n * 16 + lr) * 32 + lk]);
#pragma unroll
    for (int m = 0; m < 4; ++m)
#pragma unroll
      for (int n = 0; n < 4; ++n)
        acc[m][n] = __builtin_amdgcn_mfma_f32_16x16x32_bf16(af[m], bfr[n], acc[m][n], 0, 0, 0);
    __syncthreads();
    cur ^= 1;
  }
#undef STAGE_PHS

#pragma unroll
  for (int m = 0; m < 4; ++m)
#pragma unroll
    for (int n = 0; n < 4; ++n)
#pragma unroll
      for (int j = 0; j < 4; ++j)
        smem[(wr * 64 + m * 16 + lg + j) * 128 + wc * 64 + n * 16 + lr] =
            (bf16)acc[m][n][j];
  __syncthreads();
  bf16* Co = Cp + ((long)kc * BATCH + b) * NQ * HIDDEN;
  const long rb = (long)row * 128, cb = (long)col * 128;
#pragma unroll
  for (int i = 0; i < 8; ++i) {
    const int ch = tid + i * 256;
    const int rr = ch >> 4;
    const int ce = (ch & 15) * 8;
    *reinterpret_cast<bf16x8*>(&Co[(rb + rr) * HIDDEN + cb + ce]) =
        *reinterpret_cast<const bf16x8*>(smem + ch * 8);
  }
}

// ctx1 = (sum of 8 bf16 partials) / rowsum[row]   (fp32 accumulate, bf16 out)
__global__ __launch_bounds__(256) void k_reduce8(const bf16* __restrict__ p,
                                                 const float* __restrict__ rs,
                                                 bf16* __restrict__ out, int n8) {
  const long NB = (long)BATCH * NQ * HIDDEN;
  const int stride = gridDim.x * blockDim.x;
  for (int i = blockIdx.x * blockDim.x + threadIdx.x; i < n8; i += stride) {
    float acc[8] = {};
#pragma unroll
    for (int k = 0; k < PHS_KS; ++k) {
      bf16x8 v = reinterpret_cast<const bf16x8*>(p + k * NB)[i];
#pragma unroll
      for (int j = 0; j < 8; ++j) acc[j] += (float)v[j];
    }
    const float inv = 1.0f / rs[i / 96];  // 96 vec8-chunks per 768-col row
    bf16x8 o;
#pragma unroll
    for (int j = 0; j < 8; ++j) o[j] = (bf16)(acc[j] * inv);
    reinterpret_cast<bf16x8*>(out)[i] = o;
  }
}

// ---------------------------------------------------------------------------
extern "C" void kernel_launch(void* const* d_in, const int* in_sizes, int n_in,
                              void* d_out, int out_size, void* d_ws, size_t ws_size,
                              hipStream_t stream) {
  const float* hs = (const float*)d_in[0];    // [B,S,H]
  const float* qu = (const float*)d_in[1];    // [B,Q,H]
  const float* mask = (const float*)d_in[2];  // [B,S]
  const float* Wq = (const float*)d_in[3];
  const float* bq = (const float*)d_in[4];
  const float* Wk = (const float*)d_in[5];
  const float* Wv = (const float*)d_in[7];
  const float* bv = (const float*)d_in[8];
  float* out = (float*)d_out;  // [B,Q,H] fp32
  // bk (d_in[6]) adds a softmax-row-constant -> cancels exactly.

  const size_t HS_N = (size_t)BATCH * SEQ * HIDDEN;
  const size_t QU_N = (size_t)BATCH * NQ * HIDDEN;
  const size_t W_N = (size_t)HIDDEN * HIDDEN;
  const size_t P_N = (size_t)BATCH * NQ * SEQ;

  char* ws = (char*)d_ws;
  size_t off = 0;
  auto alloc = [&](size_t bytes) {
    char* p = ws + off;
    off += (bytes + 255) & ~(size_t)255;
    return p;
  };

  // regionA: hsb (live through scores) / PHS partials (written after) — exact overlap
  char* regionA = alloc(HS_N * 2);
  bf16* hsb = (bf16*)regionA;
  bf16* Ppart = (bf16*)regionA;         // PHS_KS * QU_N bf16 = HS_N*2 bytes
  bf16* hsT = (bf16*)alloc(HS_N * 2);   // [B][H][S]
  bf16* Pr = (bf16*)alloc(P_N * 2);     // unnormalized probs exp(s+mb)
  bf16* qub = (bf16*)alloc(QU_N * 2);
  bf16* tmpb = (bf16*)alloc(QU_N * 2);  // folded query: qu.(Wq.Wk^T) + bq.Wk^T
  bf16* ctx1 = (bf16*)alloc(QU_N * 2);  // P.hs / rowsum
  bf16* Wkb = (bf16*)alloc(W_N * 2);
  bf16* Wqb = (bf16*)alloc(W_N * 2);
  bf16* WvT = (bf16*)alloc(W_N * 2);
  bf16* Mt = (bf16*)alloc(W_N * 2);     // Wk.Wq^T
  float* bqk = (float*)alloc(HIDDEN * 4);
  float* mbias = (float*)alloc((size_t)BATCH * SEQ * 4);
  float* rspart = (float*)alloc((size_t)BATCH * NQ * 128 * 4);  // 2 MB
  float* rowsum = (float*)alloc((size_t)BATCH * NQ * 4);

  // 1) converts + transposes + fused hs prep
  k_cvt<<<dim3(1024), dim3(256), 0, stream>>>(qu, qub, (int)(QU_N / 4));
  k_cvt<<<dim3(576), dim3(256), 0, stream>>>(Wk, Wkb, (int)(W_N / 4));
  k_cvt<<<dim3(576), dim3(256), 0, stream>>>(Wq, Wqb, (int)(W_N / 4));
  k_transpose_w<<<dim3(24, 24), dim3(256), 0, stream>>>(Wv, WvT, HIDDEN, HIDDEN);
  k_cvt_hs_dual<<<dim3(12, 1024), dim3(256), 0, stream>>>(hs, hsb, hsT);
  k_mbias<<<dim3(32), dim3(256), 0, stream>>>(mask, mbias, BATCH * SEQ / 4);
  k_gemv_bqk<<<dim3(768), dim3(64), 0, stream>>>(Wk, bq, bqk);

  // 2) Mt = Wk.Wq^T   [768x768]
  k_gemm_bt<bf16, 0><<<dim3(36), dim3(256), 0, stream>>>(
      Wkb, Wqb, Mt, nullptr, nullptr, nullptr, HIDDEN, HIDDEN, 1.0f, 6, 6, 0, 0, 0, 0);

  // 3) folded query: tmp = qub.Mt^T + bqk   [4096x768]
  k_gemm_bt<bf16, 0><<<dim3(192), dim3(256), 0, stream>>>(
      qub, Mt, tmpb, bqk, nullptr, nullptr, HIDDEN, HIDDEN, 1.0f, 6, 32, 0, 0, 0, 0);

  // 4) P = exp(tmp.hsb^T/sqrt(H) + mbias), rowsum partials (no separate softmax)
  const float qkscale = 1.0f / sqrtf((float)HIDDEN);
  k_gemm_bt<bf16, 1><<<dim3(2048), dim3(256), 0, stream>>>(
      tmpb, hsb, Pr, nullptr, mbias, rspart, SEQ, HIDDEN, qkscale, 64, 8, 1,
      (long)NQ * HIDDEN, (long)SEQ * HIDDEN, (long)NQ * SEQ);
  k_rowsum<<<dim3(BATCH * NQ / 8), dim3(256), 0, stream>>>(rspart, rowsum);

  // 5) PHS partials: Ppart[kc] = P[:, kc-chunk] . hsT^T   (overwrites dead hsb)
  k_gemm_phs<<<dim3(6 * 8 * 4 * PHS_KS), dim3(256), 0, stream>>>(Pr, hsT, Ppart);

  // 6) ctx1 = (sum partials) / rowsum
  k_reduce8<<<dim3(1536), dim3(256), 0, stream>>>(Ppart, rowsum, ctx1, (int)(QU_N / 8));

  // 7) V-fold: out = ctx1.Wv + bv   (sum_j p = 1 makes +bv exact)
  k_gemm_bt<float, 0><<<dim3(192), dim3(256), 0, stream>>>(
      ctx1, WvT, out, bv, nullptr, nullptr, HIDDEN, HIDDEN, 1.0f, 6, 32, 0, 0, 0, 0);
}